// Round 1
// 161.936 us; speedup vs baseline: 1.0565x; 1.0565x over previous
//
#include <hip/hip_runtime.h>

#define SLEN 2048
#define PATCH 16
#define ND 4
#define NW 2033          // windows per dilation = S - P + 1
#define NCAND 8132       // ND * NW
#define NROWS 256        // B * C
#define NCH 8
#define ROWPAD 8192      // padded per-row stride for convf/sel

// ws layout (bytes):
//   sel   : u16   [NROWS*ROWPAD]  @ 0         ( 4 MB)
//   convf : float [NROWS*ND*SLEN] @ 16777216  ( 8 MB)

#define CDX(x) ((x) + ((x) >> 4))   // f64 cd LDS pad
#define XSX(x) ((x) + ((x) >> 3))   // f32 xs LDS pad (breaks stride-dil bank aliasing)

// One block per row: conv (4 dilations, f64, LDS) -> can_merge (incl. boundary
// pairs, all from LDS) -> chunk-parity scan + compaction -> sel + convf out.
__global__ __launch_bounds__(512) void k1(
    const float* __restrict__ seasonal,
    const float* __restrict__ conv_w,
    const float* __restrict__ conv_b,
    float* __restrict__ convf,
    unsigned short* __restrict__ sel)
{
    const int row = blockIdx.x;          // 0..255 (= b*8 + c)
    const int b = row >> 3, c = row & 7;
    const int tid = threadIdx.x;

    __shared__ float  xs[XSX(SLEN-1)+1];          //  9.2 KB (reused as cm bytes)
    __shared__ double cd[CDX(ND*SLEN-1)+1];       // 69.6 KB padded f64 conv
    __shared__ unsigned char c0s[512];
    __shared__ int      wmax[8];
    __shared__ unsigned wsum[8];

    for (int j = tid; j < SLEN; j += 512)
        xs[XSX(j)] = seasonal[(size_t)(b*SLEN + j)*NCH + c];
    __syncthreads();

    // ---- conv: per dilation, thread -> 4 outputs spaced dil apart (tap sharing)
    for (int d = 0; d < ND; ++d) {
        const int dil = 1 << d;
        double w[PATCH];
        #pragma unroll
        for (int k = 0; k < PATCH; ++k) w[k] = (double)conv_w[d*PATCH + k];
        const double bias = (double)conv_b[d];
        const int r  = tid & (dil - 1);
        const int g  = tid >> d;                 // 0 .. 512/dil - 1
        const int bx = g*4*dil + r;              // first output index

        double xt[19];                           // taps x[bx + (q-15)*dil], q=0..18
        #pragma unroll
        for (int q = 0; q < 19; ++q) {
            int idx = bx + (q - 15)*dil;
            xt[q] = (idx >= 0) ? (double)xs[XSX(idx)] : 0.0;
        }
        double acc[4];
        #pragma unroll
        for (int m = 0; m < 4; ++m) acc[m] = 0.0;
        if (g >= 4) {                            // no clipping: all taps valid
            #pragma unroll
            for (int m = 0; m < 4; ++m)
                #pragma unroll
                for (int k = 0; k < PATCH; ++k)
                    acc[m] += w[k] * xt[m + k];
        } else {                                 // left-clip guard (exact skip)
            #pragma unroll
            for (int m = 0; m < 4; ++m)
                #pragma unroll
                for (int k = 0; k < PATCH; ++k)
                    if (4*g + m + k - 15 >= 0)
                        acc[m] += w[k] * xt[m + k];
        }
        const int ob = d*SLEN + bx;
        #pragma unroll
        for (int m = 0; m < 4; ++m)
            cd[CDX(ob + m*dil)] = acc[m] + bias;
    }
    __syncthreads();   // xs dead from here; its space becomes cm byte array

    // ---- coalesced convf writeout (float4)
    {
        float* dst = convf + (size_t)row * ROWPAD;
        #pragma unroll
        for (int j = 0; j < 4; ++j) {
            int i4 = (tid + j*512) * 4;
            float4 v;
            v.x = (float)cd[CDX(i4+0)];
            v.y = (float)cd[CDX(i4+1)];
            v.z = (float)cd[CDX(i4+2)];
            v.w = (float)cd[CDX(i4+3)];
            *(float4*)&dst[i4] = v;
        }
    }

    // ---- can_merge: 128 threads per dilation, 16 pairs each; boundaries on u==127
    unsigned char* cmL = (unsigned char*)xs;
    {
        const int d  = tid >> 7;
        const int u  = tid & 127;
        const int db = d * SLEN;
        if (u < 127) {
            const int w0 = u * 16;               // pairs w0..w0+15 (w <= 2031)
            double W1=0.0, W2=0.0, Wk=0.0;
            #pragma unroll
            for (int k = 0; k < 16; ++k) {
                double v = cd[CDX(db + w0 + k)];
                W1 += v; W2 = fma(v,v,W2); Wk = fma((double)k,v,Wk);
            }
            unsigned char* crow = cmL + d*NW;
            #pragma unroll
            for (int j = 0; j < 16; ++j) {
                double v0 = cd[CDX(db+w0+j)], v16 = cd[CDX(db+w0+j+16)];
                double nW1 = W1 + (v16 - v0);
                double nW2 = W2 + (v16*v16 - v0*v0);
                double nWk = Wk - W1 + v0 + 15.0*v16;
                double S1  = W1 + nW1;
                double S2  = W2 + nW2;
                double Sxy = (Wk - 15.5*W1) + (nWk + 0.5*nW1);
                double syy = S2 - S1*S1*(1.0/32.0);
                crow[w0+j] = (unsigned char)((Sxy*Sxy >= 1364.0*syy) && (syy > 0.0));
                W1 = nW1; W2 = nW2; Wk = nWk;
            }
        } else if (d < 3) {
            // boundary pair i = d*NW + 2032: window d[2032..2047] vs (d+1)[0..15]
            double aW1=0,aW2=0,aWk=0, bW1=0,bW2=0,bWk=0;
            #pragma unroll
            for (int k = 0; k < 16; ++k) {
                double va = cd[CDX(db + 2032 + k)];
                double vb = cd[CDX(db + SLEN + k)];
                aW1 += va; aW2 = fma(va,va,aW2); aWk = fma((double)k,va,aWk);
                bW1 += vb; bW2 = fma(vb,vb,bW2); bWk = fma((double)k,vb,bWk);
            }
            double S1  = aW1 + bW1;
            double S2  = aW2 + bW2;
            double Sxy = (aWk - 15.5*aW1) + (bWk + 0.5*bW1);
            double syy = S2 - S1*S1*(1.0/32.0);
            cmL[d*NW + 2032] = (unsigned char)((Sxy*Sxy >= 1364.0*syy) && (syy > 0.0));
        }
        if (tid < 61) cmL[NCAND - 1 + tid] = 0;  // pad-false @8131 + zero tail to 8192
    }
    __syncthreads();

    // ---- pack: 16-bit chunk per thread, chunk-parity carry, shuffle scans
    const int base = tid * 16;
    unsigned cmbits = 0;
    {
        const unsigned* cw = (const unsigned*)cmL;
        #pragma unroll
        for (int q = 0; q < 4; ++q) {
            unsigned wrd = cw[tid*4 + q];
            #pragma unroll
            for (int bb = 0; bb < 4; ++bb) {
                unsigned bit = ((wrd >> (8*bb)) & 0xffu) ? 1u : 0u;
                cmbits |= bit << (q*4 + bb);
            }
        }
    }
    unsigned inv16 = (~cmbits) & 0xffffu;
    const bool allones = (inv16 == 0u);
    unsigned T = allones ? 16u : (unsigned)__clz(inv16 << 16);
    c0s[tid] = (unsigned char)(T & 1u);
    int pm = allones ? -1 : tid;

    const int lane = tid & 63, wid = tid >> 6;
    int mscan = pm;                              // inclusive wave max-scan
    #pragma unroll
    for (int off = 1; off < 64; off <<= 1) {
        int v = __shfl_up(mscan, off);
        if (lane >= off && v > mscan) mscan = v;
    }
    if (lane == 63) wmax[wid] = mscan;
    __syncthreads();                             // c0s + wmax visible
    int pshift = __shfl_up(mscan, 1);
    int mexcl = (lane == 0) ? -1 : pshift;
    #pragma unroll
    for (int wq = 0; wq < 8; ++wq)
        if (wq < wid) { int v = wmax[wq]; if (v > mexcl) mexcl = v; }
    unsigned carry = (mexcl >= 0) ? (unsigned)c0s[mexcl] : 0u;

    int nelem = NCAND - base; if (nelem > 16) nelem = 16; if (nelem < 0) nelem = 0;
    unsigned cons = carry, validb = 0, mergeb = 0;
    int cnt = 0;
    for (int w2 = 0; w2 < nelem; ++w2) {
        unsigned bit = (cmbits >> w2) & 1u;
        unsigned val = cons ^ 1u;
        unsigned mrg = bit & val;
        validb |= val << w2;
        mergeb |= mrg << w2;
        cnt += (int)val;
        cons = mrg;
    }

    int sscan = cnt;                             // inclusive wave sum-scan
    #pragma unroll
    for (int off = 1; off < 64; off <<= 1) {
        int v = __shfl_up(sscan, off);
        if (lane >= off) sscan += v;
    }
    if (lane == 63) wsum[wid] = (unsigned)sscan;
    __syncthreads();
    unsigned wbase = 0, total = 0;
    #pragma unroll
    for (int wq = 0; wq < 8; ++wq) {
        unsigned v = wsum[wq];
        if (wq < wid) wbase += v;
        total += v;
    }
    unsigned r = wbase + (unsigned)(sscan - cnt);

    unsigned short* selrow = sel + (size_t)row * ROWPAD;
    for (int w2 = 0; w2 < nelem; ++w2) {
        if ((validb >> w2) & 1u)
            selrow[r++] = (unsigned short)(((base + w2) << 1) | (int)((mergeb >> w2) & 1u));
    }
    for (int idx = (int)total + tid; idx < NCAND; idx += 512)
        selrow[idx] = 0xFFFFu;
}

// Block = (b, chunk of 32 n). Valid i advances by 1..2 per n, so 32 n of one
// row touch a contiguous <=95-float span of convf (a(i)=i+15d monotone).
// Cooperative span load -> LDS gather -> tile -> streaming dwordx4 out.
__global__ __launch_bounds__(256) void k_out(
    const float* __restrict__ convf,
    const unsigned short* __restrict__ sel,
    float* __restrict__ out)
{
    __shared__ float gbuf[8*132];                // per-row conv spans (<=95 used)
    __shared__ int   amin_s[8], amax_s[8];
    __shared__ float tile[32*132];               // output staging, +4-word row pad

    const int t = threadIdx.x;
    const int c = t & 7;
    const int s = t >> 3;                        // 0..31
    const unsigned bq = blockIdx.x;
    const unsigned b  = bq / 255u;               // 32 batches x 255 chunks
    const unsigned m  = bq - b*255u;
    const int n0 = (int)m*32;
    const int ns = (NCAND - n0 < 32) ? (NCAND - n0) : 32;   // 32 or 4 (tail)
    const unsigned row = b*NCH + (unsigned)c;

    if (t < 8) { amin_s[t] = 0x7fffffff; amax_s[t] = -1; }
    __syncthreads();

    int e = -1, ai = 0, ai2 = 0;
    if (s < ns) {
        unsigned short e16 = sel[(size_t)row*ROWPAD + (n0 + s)];
        e = (e16 == 0xFFFFu) ? -1 : (int)e16;
        if (e >= 0) {
            const int i  = e >> 1;
            const int d  = (i >= 3*NW) ? 3 : (i >= 2*NW) ? 2 : (i >= NW) ? 1 : 0;
            ai = i + 15*d;                       // linear addr in row (d*2048 + i-d*NW)
            int ae;
            if (e & 1) {
                const int i2 = i + 1;            // i=NCAND-1 merge masked in k1
                const int d2 = (i2 >= 3*NW) ? 3 : (i2 >= 2*NW) ? 2 : (i2 >= NW) ? 1 : 0;
                ai2 = i2 + 15*d2;
                ae = ai2 + 16;
            } else {
                ai2 = ai;
                ae = ai + 16;
            }
            atomicMin(&amin_s[c], ai);
            atomicMax(&amax_s[c], ae);
        }
    }
    __syncthreads();

    {   // cooperative contiguous span load: 32 lanes per row, 8 rows
        const int r = t >> 5, j = t & 31;
        const int lo = amin_s[r], hi = amax_s[r];
        if (lo <= hi) {
            const float* src = convf + (size_t)(b*NCH + r)*8192;
            for (int o = j; o <= hi - lo; o += 32)
                gbuf[r*132 + o] = src[lo + o];
        }
    }
    __syncthreads();

    float vals[16];
    if (e < 0) {
        #pragma unroll
        for (int k = 0; k < 16; ++k) vals[k] = 0.0f;
    } else {
        const float* f = gbuf + c*132 + (ai  - amin_s[c]);
        const float* g = gbuf + c*132 + (ai2 - amin_s[c]);
        if (e & 1) {
            #pragma unroll
            for (int k = 0; k < 16; ++k) vals[k] = 0.5f*(f[k] + g[k]);
        } else {
            #pragma unroll
            for (int k = 0; k < 16; ++k) vals[k] = f[k];
        }
    }
    if (s < ns) {
        float* tr = tile + s*132 + c;
        #pragma unroll
        for (int k = 0; k < 16; ++k) tr[k*8] = vals[k];
    }
    __syncthreads();

    const size_t obase = ((size_t)b*NCAND + n0)*128;   // contiguous block range
    const int nw = ns*128;
    #pragma unroll
    for (int m2 = 0; m2 < 4; ++m2) {
        int L = (t + m2*256)*4;
        if (L < nw) {
            int s2 = L >> 7, j = L & 127;
            float4 v = *(const float4*)&tile[s2*132 + j];
            *(float4*)&out[obase + L] = v;
        }
    }
}

extern "C" void kernel_launch(void* const* d_in, const int* in_sizes, int n_in,
                              void* d_out, int out_size, void* d_ws, size_t ws_size,
                              hipStream_t stream) {
    const float* seasonal = (const float*)d_in[0];
    const float* conv_w   = (const float*)d_in[1];
    const float* conv_b   = (const float*)d_in[2];
    float* out = (float*)d_out;

    char* ws = (char*)d_ws;
    unsigned short* sel   = (unsigned short*)(ws);
    float*          convf = (float*)(ws + 16777216);

    hipLaunchKernelGGL(k1,    dim3(NROWS), dim3(512), 0, stream,
                       seasonal, conv_w, conv_b, convf, sel);
    hipLaunchKernelGGL(k_out, dim3(32*255), dim3(256), 0, stream,
                       convf, sel, out);
}